// Round 5
// baseline (377.612 us; speedup 1.0000x reference)
//
#include <hip/hip_runtime.h>
#include <cstdint>

namespace {

typedef __attribute__((ext_vector_type(8))) short bf16x8;
typedef __attribute__((ext_vector_type(4))) short bf16x4;
typedef __attribute__((ext_vector_type(4))) float f32x4;

constexpr int D  = 1024;
constexpr int H  = 16;
constexpr int DH = 64;
constexpr int B  = 2;
constexpr int S  = 2048;
constexpr int M  = B * S;          // 4096

__device__ inline unsigned short f2bf(float f) {
    union { float f; uint32_t u; } v{f};
    return (unsigned short)((v.u + 0x7fffu + ((v.u >> 16) & 1u)) >> 16);
}

__device__ inline void gload16(const void* g, void* l) {
    __builtin_amdgcn_global_load_lds(
        (const __attribute__((address_space(1))) void*)g,
        (__attribute__((address_space(3))) void*)l, 16, 0, 0);
}

// ---------------------------------------------------------------------------
// x [4096,1024] f32 -> bf16
// ---------------------------------------------------------------------------
__global__ __launch_bounds__(256) void pack_x(const float* __restrict__ x,
                                              unsigned short* __restrict__ xb) {
    const int i = (blockIdx.x * 256 + threadIdx.x) * 8;
    float4 a = *reinterpret_cast<const float4*>(&x[i]);
    float4 b = *reinterpret_cast<const float4*>(&x[i + 4]);
    bf16x8 o;
    o[0] = f2bf(a.x); o[1] = f2bf(a.y); o[2] = f2bf(a.z); o[3] = f2bf(a.w);
    o[4] = f2bf(b.x); o[5] = f2bf(b.y); o[6] = f2bf(b.z); o[7] = f2bf(b.w);
    *reinterpret_cast<bf16x8*>(&xb[i]) = o;
}

// ---------------------------------------------------------------------------
// 4 weight matrices [1024 k][1024 n] f32 -> WtAll bf16 [4][n][k]
// ---------------------------------------------------------------------------
__global__ __launch_bounds__(256) void transpose_w4(
    const float* __restrict__ W0, const float* __restrict__ W1,
    const float* __restrict__ W2, const float* __restrict__ W3,
    unsigned short* __restrict__ WtAll)
{
    __shared__ unsigned short T[64][72];
    const int z = blockIdx.z;
    const float* W = z == 0 ? W0 : (z == 1 ? W1 : (z == 2 ? W2 : W3));
    unsigned short* Wt = WtAll + (size_t)z * D * D;
    const int n0 = blockIdx.x * 64, k0 = blockIdx.y * 64;
    const int t = threadIdx.x;
    #pragma unroll
    for (int i = 0; i < 16; ++i) {
        int idx = i * 256 + t, r = idx >> 6, c = idx & 63;
        T[r][c] = f2bf(W[(size_t)(k0 + r) * D + n0 + c]);
    }
    __syncthreads();
    #pragma unroll
    for (int i = 0; i < 16; ++i) {
        int idx = i * 256 + t, r = idx >> 6, c = idx & 63;
        Wt[(size_t)(n0 + r) * D + k0 + c] = T[c][r];
    }
}

// ---------------------------------------------------------------------------
// V [bh][s][dh] bf16 -> Vt [bh][dh][s] bf16
// ---------------------------------------------------------------------------
__global__ __launch_bounds__(256) void transpose_v(const unsigned short* __restrict__ Vb,
                                                   unsigned short* __restrict__ Vt) {
    __shared__ unsigned short T[64][72];
    const int s0 = blockIdx.x * 64, bh = blockIdx.y;
    const unsigned short* src = Vb + (size_t)bh * S * DH;
    unsigned short* dst = Vt + (size_t)bh * DH * S;
    const int t = threadIdx.x;
    #pragma unroll
    for (int i = 0; i < 16; ++i) {
        int idx = i * 256 + t, r = idx >> 6, c = idx & 63;
        T[r][c] = src[(size_t)(s0 + r) * DH + c];
    }
    __syncthreads();
    #pragma unroll
    for (int i = 0; i < 16; ++i) {
        int idx = i * 256 + t, r = idx >> 6, c = idx & 63;
        dst[(size_t)r * S + s0 + c] = T[c][r];
    }
}

// ---------------------------------------------------------------------------
// MFMA GEMM, m97 structure: global_load_lds(16B) + XOR-swizzled linear LDS.
// C[M,N] = A[M,K] @ Bt[N,K]^T + bias.  128x128 tile, BK=64, 4 waves (2x2).
// SWAPPED operands: mfma(b, a) -> lane holds 1 row x 4 consecutive cols.
// MODE 0: fused QKV (N=3072): Q scaled 0.125 -> split-head bf16; K,V bf16.
// MODE 1: fp32 row-major out (final projection, N=1024).
// ---------------------------------------------------------------------------
template <int MODE>
__global__ __launch_bounds__(256) void mfma_gemm(
    const unsigned short* __restrict__ A, const unsigned short* __restrict__ Bt,
    const float* __restrict__ b0, const float* __restrict__ b1,
    const float* __restrict__ b2,
    unsigned short* __restrict__ oQ, unsigned short* __restrict__ oK,
    unsigned short* __restrict__ oV, float* __restrict__ oF)
{
    __shared__ __align__(16) unsigned short As[128 * 64];
    __shared__ __align__(16) unsigned short Bs[128 * 64];
    const int t = threadIdx.x;
    const int lane = t & 63, w = t >> 6;
    const int wr = w >> 1, wc = w & 1;
    const int lo = lane & 15, hi = lane >> 4;
    const int m0 = blockIdx.y * 128, n0 = blockIdx.x * 128;

    f32x4 acc[4][4] = {};

    for (int k0 = 0; k0 < D; k0 += 64) {
        #pragma unroll
        for (int i = 0; i < 4; ++i) {
            const int row = i * 32 + w * 8 + (lane >> 3);
            const int gcol = ((lane & 7) * 8) ^ ((row & 7) * 8);  // src pre-swizzle
            gload16(&A[(size_t)(m0 + row) * D + k0 + gcol], &As[i * 2048 + w * 512]);
            gload16(&Bt[(size_t)(n0 + row) * D + k0 + gcol], &Bs[i * 2048 + w * 512]);
        }
        __syncthreads();
        #pragma unroll
        for (int kk = 0; kk < 2; ++kk) {
            bf16x8 a[4], b[4];
            #pragma unroll
            for (int m = 0; m < 4; ++m) {
                const int row = wr * 64 + m * 16 + lo;
                a[m] = *reinterpret_cast<const bf16x8*>(
                    &As[row * 64 + ((kk * 32 + hi * 8) ^ ((row & 7) * 8))]);
            }
            #pragma unroll
            for (int n = 0; n < 4; ++n) {
                const int row = wc * 64 + n * 16 + lo;
                b[n] = *reinterpret_cast<const bf16x8*>(
                    &Bs[row * 64 + ((kk * 32 + hi * 8) ^ ((row & 7) * 8))]);
            }
            #pragma unroll
            for (int m = 0; m < 4; ++m)
                #pragma unroll
                for (int n = 0; n < 4; ++n)
                    acc[m][n] = __builtin_amdgcn_mfma_f32_16x16x32_bf16(b[n], a[m], acc[m][n], 0, 0, 0);
        }
        __syncthreads();
    }

    // acc[m][n][r]: row = m0+wr*64+m*16+lo, col = n0+wc*64+n*16+hi*4+r
    if (MODE == 0) {
        const int which = n0 >> 10;                 // uniform per block
        const float* bs = which == 0 ? b0 : (which == 1 ? b1 : b2);
        unsigned short* op = which == 0 ? oQ : (which == 1 ? oK : oV);
        const float scale = which == 0 ? 0.125f : 1.0f;
        #pragma unroll
        for (int m = 0; m < 4; ++m) {
            const int row = m0 + wr * 64 + m * 16 + lo;
            const int b_ = row >> 11, s_ = row & (S - 1);
            #pragma unroll
            for (int n = 0; n < 4; ++n) {
                const int nn = (n0 + wc * 64 + n * 16 + hi * 4) & 1023;
                const int h_ = nn >> 6, dh = nn & 63;
                float4 bv = *reinterpret_cast<const float4*>(&bs[nn]);
                bf16x4 o;
                #pragma unroll
                for (int r = 0; r < 4; ++r)
                    o[r] = (short)f2bf((acc[m][n][r] + (&bv.x)[r]) * scale);
                *reinterpret_cast<bf16x4*>(
                    &op[(((size_t)(b_ * H + h_) * S) + s_) * DH + dh]) = o;
            }
        }
    } else {
        #pragma unroll
        for (int m = 0; m < 4; ++m) {
            const int row = m0 + wr * 64 + m * 16 + lo;
            #pragma unroll
            for (int n = 0; n < 4; ++n) {
                const int colb = n0 + wc * 64 + n * 16 + hi * 4;
                float4 bv = *reinterpret_cast<const float4*>(&b0[colb]);
                f32x4 v;
                #pragma unroll
                for (int r = 0; r < 4; ++r) v[r] = acc[m][n][r] + (&bv.x)[r];
                *reinterpret_cast<f32x4*>(&oF[(size_t)row * D + colb]) = v;
            }
        }
    }
}

// ---------------------------------------------------------------------------
// Pass 1: per-row sumexp (m=0: logits are O(10), exp never overflows fp32).
// Swapped QK^T: lane lo owns q-row q0+lo; 2 shfl_xor reduce over hi groups.
// ---------------------------------------------------------------------------
__global__ __launch_bounds__(256) void attn_stats(
    const unsigned short* __restrict__ Q, const unsigned short* __restrict__ K,
    float* __restrict__ lrow)
{
    const int bh = blockIdx.x;
    const int qt = (S / 64 - 1) - blockIdx.y;
    const int t = threadIdx.x, lane = t & 63, w = t >> 6;
    const int lo = lane & 15, hi = lane >> 4;
    const int q0 = qt * 64 + w * 16;
    const int myq = q0 + lo;
    const unsigned short* Qb = Q + (size_t)bh * S * DH;
    const unsigned short* Kb = K + (size_t)bh * S * DH;

    bf16x8 aq[2];
    #pragma unroll
    for (int kk = 0; kk < 2; ++kk)
        aq[kk] = *reinterpret_cast<const bf16x8*>(&Qb[(size_t)(q0 + lo) * DH + kk * 32 + hi * 8]);

    float psum = 0.f;

    for (int jt = 0; jt <= qt; ++jt) {
        f32x4 acc[4] = {};
        #pragma unroll
        for (int kk = 0; kk < 2; ++kk)
            #pragma unroll
            for (int n = 0; n < 4; ++n) {
                bf16x8 bk = *reinterpret_cast<const bf16x8*>(
                    &Kb[(size_t)(jt * 64 + n * 16 + lo) * DH + kk * 32 + hi * 8]);
                acc[n] = __builtin_amdgcn_mfma_f32_16x16x32_bf16(bk, aq[kk], acc[n], 0, 0, 0);
            }
        #pragma unroll
        for (int n = 0; n < 4; ++n)
            #pragma unroll
            for (int r = 0; r < 4; ++r) {
                const int j = jt * 64 + n * 16 + hi * 4 + r;
                psum += (j <= myq) ? __expf(acc[n][r]) : 0.f;
            }
    }
    psum += __shfl_xor(psum, 16);
    psum += __shfl_xor(psum, 32);
    if (lane < 16) lrow[(size_t)bh * S + myq] = 1.0f / psum;
}

// ---------------------------------------------------------------------------
// Pass 2: recompute QK^T (swapped), p = exp(s)*li; direct nontemporal f32x4
// P-stores from registers; bf16 LDS round-trip only for the PV A-fragments.
// PV also swapped -> ctx written as bf16x4 vectors.
// ---------------------------------------------------------------------------
__global__ __launch_bounds__(256) void attn_probs_ctx(
    const unsigned short* __restrict__ Q, const unsigned short* __restrict__ K,
    const unsigned short* __restrict__ Vt, const float* __restrict__ lrow,
    float* __restrict__ P, unsigned short* __restrict__ ctxb)
{
    __shared__ __align__(16) unsigned short Pf[4][16][72];
    const int bh = blockIdx.x;
    const int qt = (S / 64 - 1) - blockIdx.y;
    const int t = threadIdx.x, lane = t & 63, w = t >> 6;
    const int lo = lane & 15, hi = lane >> 4;
    const int q0 = qt * 64 + w * 16;
    const int myq = q0 + lo;
    const unsigned short* Qb = Q + (size_t)bh * S * DH;
    const unsigned short* Kb = K + (size_t)bh * S * DH;
    const unsigned short* Vb = Vt + (size_t)bh * DH * S;
    float* Pb = P + (size_t)bh * S * S;
    unsigned short (*pf)[72] = Pf[w];

    bf16x8 aq[2];
    #pragma unroll
    for (int kk = 0; kk < 2; ++kk)
        aq[kk] = *reinterpret_cast<const bf16x8*>(&Qb[(size_t)(q0 + lo) * DH + kk * 32 + hi * 8]);

    const float li = lrow[(size_t)bh * S + myq];

    f32x4 actx[4] = {};

    for (int jt = 0; jt <= qt; ++jt) {
        f32x4 acc[4] = {};
        #pragma unroll
        for (int kk = 0; kk < 2; ++kk)
            #pragma unroll
            for (int n = 0; n < 4; ++n) {
                bf16x8 bk = *reinterpret_cast<const bf16x8*>(
                    &Kb[(size_t)(jt * 64 + n * 16 + lo) * DH + kk * 32 + hi * 8]);
                acc[n] = __builtin_amdgcn_mfma_f32_16x16x32_bf16(bk, aq[kk], acc[n], 0, 0, 0);
            }
        // p = exp(s)*li, masked; direct vector store + bf16 into per-wave LDS
        #pragma unroll
        for (int n = 0; n < 4; ++n) {
            f32x4 pv4;
            #pragma unroll
            for (int r = 0; r < 4; ++r) {
                const int j = jt * 64 + n * 16 + hi * 4 + r;
                float p = (j <= myq) ? __expf(acc[n][r]) * li : 0.f;
                pv4[r] = p;
                pf[lo][n * 16 + hi * 4 + r] = f2bf(p);
            }
            __builtin_nontemporal_store(
                pv4, reinterpret_cast<f32x4*>(&Pb[(size_t)myq * S + jt * 64 + n * 16 + hi * 4]));
        }
        // PV (swapped): A = Vt frag (rows = dh), B = p frag (rows = q)
        #pragma unroll
        for (int kk = 0; kk < 2; ++kk) {
            bf16x8 pa = *reinterpret_cast<const bf16x8*>(&pf[lo][kk * 32 + hi * 8]);
            #pragma unroll
            for (int n2 = 0; n2 < 4; ++n2) {
                bf16x8 bv = *reinterpret_cast<const bf16x8*>(
                    &Vb[(size_t)(n2 * 16 + lo) * S + jt * 64 + kk * 32 + hi * 8]);
                actx[n2] = __builtin_amdgcn_mfma_f32_16x16x32_bf16(bv, pa, actx[n2], 0, 0, 0);
            }
        }
    }

    // zero-fill strictly-upper tiles of P
    const f32x4 z = {0.f, 0.f, 0.f, 0.f};
    for (int jt = qt + 1; jt < S / 64; ++jt)
        #pragma unroll
        for (int rr = 0; rr < 4; ++rr) {
            const int qrow = q0 + rr * 4 + hi;
            __builtin_nontemporal_store(
                z, reinterpret_cast<f32x4*>(&Pb[(size_t)qrow * S + jt * 64 + lo * 4]));
        }

    // ctx -> merged-head bf16 [b*S+q][h*64+dh]; lane owns row myq, 4 cols
    const int b_ = bh >> 4, h_ = bh & 15;
    #pragma unroll
    for (int n2 = 0; n2 < 4; ++n2) {
        bf16x4 o;
        #pragma unroll
        for (int r = 0; r < 4; ++r) o[r] = (short)f2bf(actx[n2][r]);
        *reinterpret_cast<bf16x4*>(
            &ctxb[((size_t)(b_ * S + myq)) * D + h_ * 64 + n2 * 16 + hi * 4]) = o;
    }
}

}  // namespace

extern "C" void kernel_launch(void* const* d_in, const int* in_sizes, int n_in,
                              void* d_out, int out_size, void* d_ws, size_t ws_size,
                              hipStream_t stream) {
    const float* x  = (const float*)d_in[0];
    const float* Wq = (const float*)d_in[2];
    const float* bq = (const float*)d_in[3];
    const float* Wk = (const float*)d_in[4];
    const float* bk = (const float*)d_in[5];
    const float* Wv = (const float*)d_in[6];
    const float* bv = (const float*)d_in[7];
    const float* Wo = (const float*)d_in[8];
    const float* bo = (const float*)d_in[9];

    float* out = (float*)d_out;
    float* P   = out + (size_t)M * D;

    char* ws = (char*)d_ws;
    const size_t MB = 1u << 20;
    unsigned short* xb    = (unsigned short*)(ws);            // 8 MB
    unsigned short* WtAll = (unsigned short*)(ws + 8 * MB);   // 8 MB  [Wq|Wk|Wv|Wo] transposed
    unsigned short* Qb    = (unsigned short*)(ws + 16 * MB);  // 8 MB
    unsigned short* Kb    = (unsigned short*)(ws + 24 * MB);  // 8 MB
    unsigned short* Vtmp  = (unsigned short*)(ws + 32 * MB);  // 8 MB
    unsigned short* Vtb   = (unsigned short*)(ws + 40 * MB);  // 8 MB
    unsigned short* ctxb  = (unsigned short*)(ws + 48 * MB);  // 8 MB
    float* lrow           = (float*)(ws + 56 * MB);           // 256 KB

    const dim3 blk(256);

    pack_x<<<dim3(M * D / (256 * 8)), blk, 0, stream>>>(x, xb);
    transpose_w4<<<dim3(16, 16, 4), blk, 0, stream>>>(Wq, Wk, Wv, Wo, WtAll);

    // fused QKV projection: N = 3072
    mfma_gemm<0><<<dim3(24, M / 128), blk, 0, stream>>>(
        xb, WtAll, bq, bk, bv, Qb, Kb, Vtmp, nullptr);
    transpose_v<<<dim3(S / 64, B * H), blk, 0, stream>>>(Vtmp, Vtb);

    attn_stats<<<dim3(B * H, S / 64), blk, 0, stream>>>(Qb, Kb, lrow);
    attn_probs_ctx<<<dim3(B * H, S / 64), blk, 0, stream>>>(Qb, Kb, Vtb, lrow, P, ctxb);

    // output projection
    mfma_gemm<1><<<dim3(8, M / 128), blk, 0, stream>>>(
        ctxb, WtAll + (size_t)3 * D * D, bo, nullptr, nullptr,
        nullptr, nullptr, nullptr, out);
}

// Round 6
// 368.179 us; speedup vs baseline: 1.0256x; 1.0256x over previous
//
#include <hip/hip_runtime.h>
#include <cstdint>

namespace {

typedef __attribute__((ext_vector_type(8))) short bf16x8;
typedef __attribute__((ext_vector_type(4))) short bf16x4;
typedef __attribute__((ext_vector_type(4))) float f32x4;

constexpr int D  = 1024;
constexpr int H  = 16;
constexpr int DH = 64;
constexpr int B  = 2;
constexpr int S  = 2048;
constexpr int M  = B * S;          // 4096

__device__ inline unsigned short f2bf(float f) {
    union { float f; uint32_t u; } v{f};
    return (unsigned short)((v.u + 0x7fffu + ((v.u >> 16) & 1u)) >> 16);
}

__device__ inline float bf2f(unsigned short b) {
    union { uint32_t u; float f; } v;
    v.u = ((uint32_t)b) << 16;
    return v.f;
}

__device__ inline void gload16(const void* g, void* l) {
    __builtin_amdgcn_global_load_lds(
        (const __attribute__((address_space(1))) void*)g,
        (__attribute__((address_space(3))) void*)l, 16, 0, 0);
}

// ---------------------------------------------------------------------------
// x [4096,1024] f32 -> bf16
// ---------------------------------------------------------------------------
__global__ __launch_bounds__(256) void pack_x(const float* __restrict__ x,
                                              unsigned short* __restrict__ xb) {
    const int i = (blockIdx.x * 256 + threadIdx.x) * 8;
    float4 a = *reinterpret_cast<const float4*>(&x[i]);
    float4 b = *reinterpret_cast<const float4*>(&x[i + 4]);
    bf16x8 o;
    o[0] = f2bf(a.x); o[1] = f2bf(a.y); o[2] = f2bf(a.z); o[3] = f2bf(a.w);
    o[4] = f2bf(b.x); o[5] = f2bf(b.y); o[6] = f2bf(b.z); o[7] = f2bf(b.w);
    *reinterpret_cast<bf16x8*>(&xb[i]) = o;
}

// ---------------------------------------------------------------------------
// 4 weight matrices [1024 k][1024 n] f32 -> WtAll bf16 [4][n][k]
// ---------------------------------------------------------------------------
__global__ __launch_bounds__(256) void transpose_w4(
    const float* __restrict__ W0, const float* __restrict__ W1,
    const float* __restrict__ W2, const float* __restrict__ W3,
    unsigned short* __restrict__ WtAll)
{
    __shared__ unsigned short T[64][72];
    const int z = blockIdx.z;
    const float* W = z == 0 ? W0 : (z == 1 ? W1 : (z == 2 ? W2 : W3));
    unsigned short* Wt = WtAll + (size_t)z * D * D;
    const int n0 = blockIdx.x * 64, k0 = blockIdx.y * 64;
    const int t = threadIdx.x;
    #pragma unroll
    for (int i = 0; i < 16; ++i) {
        int idx = i * 256 + t, r = idx >> 6, c = idx & 63;
        T[r][c] = f2bf(W[(size_t)(k0 + r) * D + n0 + c]);
    }
    __syncthreads();
    #pragma unroll
    for (int i = 0; i < 16; ++i) {
        int idx = i * 256 + t, r = idx >> 6, c = idx & 63;
        Wt[(size_t)(n0 + r) * D + k0 + c] = T[c][r];
    }
}

// ---------------------------------------------------------------------------
// V [bh][s][dh] bf16 -> Vt [bh][dh][s] bf16
// ---------------------------------------------------------------------------
__global__ __launch_bounds__(256) void transpose_v(const unsigned short* __restrict__ Vb,
                                                   unsigned short* __restrict__ Vt) {
    __shared__ unsigned short T[64][72];
    const int s0 = blockIdx.x * 64, bh = blockIdx.y;
    const unsigned short* src = Vb + (size_t)bh * S * DH;
    unsigned short* dst = Vt + (size_t)bh * DH * S;
    const int t = threadIdx.x;
    #pragma unroll
    for (int i = 0; i < 16; ++i) {
        int idx = i * 256 + t, r = idx >> 6, c = idx & 63;
        T[r][c] = src[(size_t)(s0 + r) * DH + c];
    }
    __syncthreads();
    #pragma unroll
    for (int i = 0; i < 16; ++i) {
        int idx = i * 256 + t, r = idx >> 6, c = idx & 63;
        dst[(size_t)r * S + s0 + c] = T[c][r];
    }
}

// ---------------------------------------------------------------------------
// Fused QKV projection (m97 structure), swapped MFMA -> row-fragment output.
// C = A[M,1024] @ Wt[3072,1024]^T + bias; Q scaled 0.125; split-head bf16.
// ---------------------------------------------------------------------------
__global__ __launch_bounds__(256) void qkv_gemm(
    const unsigned short* __restrict__ A, const unsigned short* __restrict__ Bt,
    const float* __restrict__ b0, const float* __restrict__ b1,
    const float* __restrict__ b2,
    unsigned short* __restrict__ oQ, unsigned short* __restrict__ oK,
    unsigned short* __restrict__ oV)
{
    __shared__ __align__(16) unsigned short As[128 * 64];
    __shared__ __align__(16) unsigned short Bs[128 * 64];
    const int t = threadIdx.x;
    const int lane = t & 63, w = t >> 6;
    const int wr = w >> 1, wc = w & 1;
    const int lo = lane & 15, hi = lane >> 4;
    const int m0 = blockIdx.y * 128, n0 = blockIdx.x * 128;

    f32x4 acc[4][4] = {};

    for (int k0 = 0; k0 < D; k0 += 64) {
        #pragma unroll
        for (int i = 0; i < 4; ++i) {
            const int row = i * 32 + w * 8 + (lane >> 3);
            const int gcol = ((lane & 7) * 8) ^ ((row & 7) * 8);  // src pre-swizzle
            gload16(&A[(size_t)(m0 + row) * D + k0 + gcol], &As[i * 2048 + w * 512]);
            gload16(&Bt[(size_t)(n0 + row) * D + k0 + gcol], &Bs[i * 2048 + w * 512]);
        }
        __syncthreads();
        #pragma unroll
        for (int kk = 0; kk < 2; ++kk) {
            bf16x8 a[4], b[4];
            #pragma unroll
            for (int m = 0; m < 4; ++m) {
                const int row = wr * 64 + m * 16 + lo;
                a[m] = *reinterpret_cast<const bf16x8*>(
                    &As[row * 64 + ((kk * 32 + hi * 8) ^ ((row & 7) * 8))]);
            }
            #pragma unroll
            for (int n = 0; n < 4; ++n) {
                const int row = wc * 64 + n * 16 + lo;
                b[n] = *reinterpret_cast<const bf16x8*>(
                    &Bs[row * 64 + ((kk * 32 + hi * 8) ^ ((row & 7) * 8))]);
            }
            #pragma unroll
            for (int m = 0; m < 4; ++m)
                #pragma unroll
                for (int n = 0; n < 4; ++n)
                    acc[m][n] = __builtin_amdgcn_mfma_f32_16x16x32_bf16(b[n], a[m], acc[m][n], 0, 0, 0);
        }
        __syncthreads();
    }

    const int which = n0 >> 10;                 // uniform per block
    const float* bs = which == 0 ? b0 : (which == 1 ? b1 : b2);
    unsigned short* op = which == 0 ? oQ : (which == 1 ? oK : oV);
    const float scale = which == 0 ? 0.125f : 1.0f;
    #pragma unroll
    for (int m = 0; m < 4; ++m) {
        const int row = m0 + wr * 64 + m * 16 + lo;
        const int b_ = row >> 11, s_ = row & (S - 1);
        #pragma unroll
        for (int n = 0; n < 4; ++n) {
            const int nn = (n0 + wc * 64 + n * 16 + hi * 4) & 1023;
            const int h_ = nn >> 6, dh = nn & 63;
            float4 bv = *reinterpret_cast<const float4*>(&bs[nn]);
            bf16x4 o;
            #pragma unroll
            for (int r = 0; r < 4; ++r)
                o[r] = (short)f2bf((acc[m][n][r] + (&bv.x)[r]) * scale);
            *reinterpret_cast<bf16x4*>(
                &op[(((size_t)(b_ * H + h_) * S) + s_) * DH + dh]) = o;
        }
    }
}

// ---------------------------------------------------------------------------
// Pass 1 (flash-style, m=0): QK^T -> e=exp(s) masked; accumulate rowsum AND
// ctx = (sum e*V) * 1/l.  Writes lrow (1/l) and ctxb.  No P traffic.
// ---------------------------------------------------------------------------
__global__ __launch_bounds__(256) void attn_fused(
    const unsigned short* __restrict__ Q, const unsigned short* __restrict__ K,
    const unsigned short* __restrict__ Vt, float* __restrict__ lrow,
    unsigned short* __restrict__ ctxb)
{
    __shared__ __align__(16) unsigned short Pf[4][16][72];
    const int bh = blockIdx.x;
    const int qt = (S / 64 - 1) - blockIdx.y;
    const int t = threadIdx.x, lane = t & 63, w = t >> 6;
    const int lo = lane & 15, hi = lane >> 4;
    const int q0 = qt * 64 + w * 16;
    const int myq = q0 + lo;
    const unsigned short* Qb = Q + (size_t)bh * S * DH;
    const unsigned short* Kb = K + (size_t)bh * S * DH;
    const unsigned short* Vb = Vt + (size_t)bh * DH * S;
    unsigned short (*pf)[72] = Pf[w];

    bf16x8 aq[2];
    #pragma unroll
    for (int kk = 0; kk < 2; ++kk)
        aq[kk] = *reinterpret_cast<const bf16x8*>(&Qb[(size_t)myq * DH + kk * 32 + hi * 8]);

    f32x4 actx[4] = {};
    float rs[4] = {0.f, 0.f, 0.f, 0.f};

    for (int jt = 0; jt <= qt; ++jt) {
        f32x4 acc[4] = {};
        #pragma unroll
        for (int kk = 0; kk < 2; ++kk)
            #pragma unroll
            for (int n = 0; n < 4; ++n) {
                bf16x8 bk = *reinterpret_cast<const bf16x8*>(
                    &Kb[(size_t)(jt * 64 + n * 16 + lo) * DH + kk * 32 + hi * 8]);
                acc[n] = __builtin_amdgcn_mfma_f32_16x16x32_bf16(bk, aq[kk], acc[n], 0, 0, 0);
            }
        #pragma unroll
        for (int n = 0; n < 4; ++n) {
            bf16x4 ev;
            #pragma unroll
            for (int r = 0; r < 4; ++r) {
                const int j = jt * 64 + n * 16 + hi * 4 + r;
                const float e = (j <= myq) ? __expf(acc[n][r]) : 0.f;
                rs[n] += e;
                ev[r] = (short)f2bf(e);
            }
            *reinterpret_cast<bf16x4*>(&pf[lo][n * 16 + hi * 4]) = ev;
        }
        #pragma unroll
        for (int kk = 0; kk < 2; ++kk) {
            bf16x8 pa = *reinterpret_cast<const bf16x8*>(&pf[lo][kk * 32 + hi * 8]);
            #pragma unroll
            for (int n2 = 0; n2 < 4; ++n2) {
                bf16x8 bv = *reinterpret_cast<const bf16x8*>(
                    &Vb[(size_t)(n2 * 16 + lo) * S + jt * 64 + kk * 32 + hi * 8]);
                actx[n2] = __builtin_amdgcn_mfma_f32_16x16x32_bf16(bv, pa, actx[n2], 0, 0, 0);
            }
        }
    }

    float l = (rs[0] + rs[1]) + (rs[2] + rs[3]);
    l += __shfl_xor(l, 16);
    l += __shfl_xor(l, 32);
    const float inv = 1.0f / l;
    if (lane < 16) lrow[(size_t)bh * S + myq] = inv;

    const int b_ = bh >> 4, h_ = bh & 15;
    #pragma unroll
    for (int n2 = 0; n2 < 4; ++n2) {
        bf16x4 o;
        #pragma unroll
        for (int r = 0; r < 4; ++r) o[r] = (short)f2bf(actx[n2][r] * inv);
        *reinterpret_cast<bf16x4*>(
            &ctxb[((size_t)(b_ * S + myq)) * D + h_ * 64 + n2 * 16 + hi * 4]) = o;
    }
}

// ---------------------------------------------------------------------------
// Heterogeneous pass 2: 1280 blocks.
//   blocks with g%5==4 (256): out-projection GEMM tile (compute-bound)
//   others (1024): P-writer (write-bound) -> overlap hides the GEMM.
// P-writer: swapped QK^T, p=exp(s)*li, bf16 LDS stage, coalesced 256B
// nontemporal fp32 stores, zero-fill upper triangle.
// ---------------------------------------------------------------------------
__global__ __launch_bounds__(256) void probs_outproj(
    const unsigned short* __restrict__ Q, const unsigned short* __restrict__ K,
    const float* __restrict__ lrow, float* __restrict__ P,
    const unsigned short* __restrict__ ctxb, const unsigned short* __restrict__ Wto,
    const float* __restrict__ bo, float* __restrict__ out)
{
    __shared__ __align__(16) unsigned short smem[2 * 128 * 64];   // 32 KB
    const int g = blockIdx.x;
    const int q5 = g / 5, r5 = g - q5 * 5;
    const int t = threadIdx.x, lane = t & 63, w = t >> 6;
    const int lo = lane & 15, hi = lane >> 4;

    if (r5 == 4) {
        // ---- out-projection GEMM tile (gemm_id = q5: 8 n-tiles x 32 m-tiles)
        unsigned short* As = smem;
        unsigned short* Bs = smem + 128 * 64;
        const int wr = w >> 1, wc = w & 1;
        const int m0 = (q5 >> 3) * 128, n0 = (q5 & 7) * 128;

        f32x4 acc[4][4] = {};
        for (int k0 = 0; k0 < D; k0 += 64) {
            #pragma unroll
            for (int i = 0; i < 4; ++i) {
                const int row = i * 32 + w * 8 + (lane >> 3);
                const int gcol = ((lane & 7) * 8) ^ ((row & 7) * 8);
                gload16(&ctxb[(size_t)(m0 + row) * D + k0 + gcol], &As[i * 2048 + w * 512]);
                gload16(&Wto[(size_t)(n0 + row) * D + k0 + gcol], &Bs[i * 2048 + w * 512]);
            }
            __syncthreads();
            #pragma unroll
            for (int kk = 0; kk < 2; ++kk) {
                bf16x8 a[4], b[4];
                #pragma unroll
                for (int m = 0; m < 4; ++m) {
                    const int row = wr * 64 + m * 16 + lo;
                    a[m] = *reinterpret_cast<const bf16x8*>(
                        &As[row * 64 + ((kk * 32 + hi * 8) ^ ((row & 7) * 8))]);
                }
                #pragma unroll
                for (int n = 0; n < 4; ++n) {
                    const int row = wc * 64 + n * 16 + lo;
                    b[n] = *reinterpret_cast<const bf16x8*>(
                        &Bs[row * 64 + ((kk * 32 + hi * 8) ^ ((row & 7) * 8))]);
                }
                #pragma unroll
                for (int m = 0; m < 4; ++m)
                    #pragma unroll
                    for (int n = 0; n < 4; ++n)
                        acc[m][n] = __builtin_amdgcn_mfma_f32_16x16x32_bf16(b[n], a[m], acc[m][n], 0, 0, 0);
            }
            __syncthreads();
        }
        #pragma unroll
        for (int m = 0; m < 4; ++m) {
            const int row = m0 + wr * 64 + m * 16 + lo;
            #pragma unroll
            for (int n = 0; n < 4; ++n) {
                const int colb = n0 + wc * 64 + n * 16 + hi * 4;
                float4 bv = *reinterpret_cast<const float4*>(&bo[colb]);
                f32x4 v;
                #pragma unroll
                for (int r = 0; r < 4; ++r) v[r] = acc[m][n][r] + (&bv.x)[r];
                *reinterpret_cast<f32x4*>(&out[(size_t)row * D + colb]) = v;
            }
        }
        return;
    }

    // ---- P-writer block
    unsigned short (*pf)[72] = reinterpret_cast<unsigned short (*)[72]>(
        smem + (size_t)w * 16 * 72);
    const int pid = q5 * 4 + r5;                 // 0..1023
    const int bh = pid & 31;
    const int qt = (S / 64 - 1) - (pid >> 5);    // heavy first
    const int q0 = qt * 64 + w * 16;
    const int myq = q0 + lo;
    const unsigned short* Qb = Q + (size_t)bh * S * DH;
    const unsigned short* Kb = K + (size_t)bh * S * DH;
    float* Pb = P + (size_t)bh * S * S;

    bf16x8 aq[2];
    #pragma unroll
    for (int kk = 0; kk < 2; ++kk)
        aq[kk] = *reinterpret_cast<const bf16x8*>(&Qb[(size_t)myq * DH + kk * 32 + hi * 8]);

    const float li = lrow[(size_t)bh * S + myq];

    for (int jt = 0; jt <= qt; ++jt) {
        f32x4 acc[4] = {};
        #pragma unroll
        for (int kk = 0; kk < 2; ++kk)
            #pragma unroll
            for (int n = 0; n < 4; ++n) {
                bf16x8 bk = *reinterpret_cast<const bf16x8*>(
                    &Kb[(size_t)(jt * 64 + n * 16 + lo) * DH + kk * 32 + hi * 8]);
                acc[n] = __builtin_amdgcn_mfma_f32_16x16x32_bf16(bk, aq[kk], acc[n], 0, 0, 0);
            }
        #pragma unroll
        for (int n = 0; n < 4; ++n) {
            bf16x4 ev;
            #pragma unroll
            for (int r = 0; r < 4; ++r) {
                const int j = jt * 64 + n * 16 + hi * 4 + r;
                const float p = (j <= myq) ? __expf(acc[n][r]) * li : 0.f;
                ev[r] = (short)f2bf(p);
            }
            *reinterpret_cast<bf16x4*>(&pf[lo][n * 16 + hi * 4]) = ev;
        }
        // coalesced stores: 4 rows x 256B per instruction
        #pragma unroll
        for (int i2 = 0; i2 < 4; ++i2) {
            bf16x4 pv = *reinterpret_cast<const bf16x4*>(&pf[i2 * 4 + hi][lo * 4]);
            f32x4 v;
            #pragma unroll
            for (int r = 0; r < 4; ++r) v[r] = bf2f((unsigned short)pv[r]);
            __builtin_nontemporal_store(
                v, reinterpret_cast<f32x4*>(&Pb[(size_t)(q0 + i2 * 4 + hi) * S + jt * 64 + lo * 4]));
        }
    }

    // zero-fill strictly-upper tiles of P
    const f32x4 z = {0.f, 0.f, 0.f, 0.f};
    for (int jt = qt + 1; jt < S / 64; ++jt)
        #pragma unroll
        for (int rr = 0; rr < 4; ++rr) {
            const int qrow = q0 + rr * 4 + hi;
            __builtin_nontemporal_store(
                z, reinterpret_cast<f32x4*>(&Pb[(size_t)qrow * S + jt * 64 + lo * 4]));
        }
}

}  // namespace

extern "C" void kernel_launch(void* const* d_in, const int* in_sizes, int n_in,
                              void* d_out, int out_size, void* d_ws, size_t ws_size,
                              hipStream_t stream) {
    const float* x  = (const float*)d_in[0];
    const float* Wq = (const float*)d_in[2];
    const float* bq = (const float*)d_in[3];
    const float* Wk = (const float*)d_in[4];
    const float* bk = (const float*)d_in[5];
    const float* Wv = (const float*)d_in[6];
    const float* bv = (const float*)d_in[7];
    const float* Wo = (const float*)d_in[8];
    const float* bo = (const float*)d_in[9];

    float* out = (float*)d_out;
    float* P   = out + (size_t)M * D;

    char* ws = (char*)d_ws;
    const size_t MB = 1u << 20;
    unsigned short* xb    = (unsigned short*)(ws);            // 8 MB
    unsigned short* WtAll = (unsigned short*)(ws + 8 * MB);   // 8 MB  [Wq|Wk|Wv|Wo] transposed
    unsigned short* Qb    = (unsigned short*)(ws + 16 * MB);  // 8 MB
    unsigned short* Kb    = (unsigned short*)(ws + 24 * MB);  // 8 MB
    unsigned short* Vtmp  = (unsigned short*)(ws + 32 * MB);  // 8 MB
    unsigned short* Vtb   = (unsigned short*)(ws + 40 * MB);  // 8 MB
    unsigned short* ctxb  = (unsigned short*)(ws + 48 * MB);  // 8 MB
    float* lrow           = (float*)(ws + 56 * MB);           // 256 KB

    const dim3 blk(256);

    pack_x<<<dim3(M * D / (256 * 8)), blk, 0, stream>>>(x, xb);
    transpose_w4<<<dim3(16, 16, 4), blk, 0, stream>>>(Wq, Wk, Wv, Wo, WtAll);

    // fused QKV projection: N = 3072
    qkv_gemm<<<dim3(24, M / 128), blk, 0, stream>>>(
        xb, WtAll, bq, bk, bv, Qb, Kb, Vtmp);
    transpose_v<<<dim3(S / 64, B * H), blk, 0, stream>>>(Vtmp, Vtb);

    // pass 1: rowsum + ctx (flash-style, m=0)
    attn_fused<<<dim3(B * H, S / 64), blk, 0, stream>>>(Qb, Kb, Vtb, lrow, ctxb);

    // pass 2: P writer + out-projection, overlapped in one dispatch
    probs_outproj<<<dim3(1280), blk, 0, stream>>>(
        Qb, Kb, lrow, P, ctxb, WtAll + (size_t)3 * D * D, bo, out);
}